// Round 1
// baseline (181.340 us; speedup 1.0000x reference)
//
#include <hip/hip_runtime.h>
#include <cstdint>

#define NPTS   16384
#define BATCH  4
#define BNP    65536
#define CIN    64
#define KNB    16
#define COUT   128
#define BN_EPS 1e-5f

typedef __attribute__((ext_vector_type(8))) short     short8;
typedef __attribute__((ext_vector_type(4))) float     f32x4;
typedef __attribute__((ext_vector_type(2))) unsigned  u32x2;
typedef __attribute__((ext_vector_type(4))) int       i32x4;

// wait until <= n vector-memory ops outstanding (lgkm=15, exp=7 = no wait)
#define WAITVM(n) __builtin_amdgcn_s_waitcnt(0x0F70 | (n))

__device__ __forceinline__ unsigned short f2bf(float f) {   // RNE
    unsigned u = __float_as_uint(f);
    u += 0x7FFFu + ((u >> 16) & 1u);
    return (unsigned short)(u >> 16);
}
__device__ __forceinline__ float bf2f(unsigned short h) {
    return __uint_as_float(((unsigned)h) << 16);
}

// ---------------- K0: feature [B][C][N] -> flat bf16 [B*N][64] ----------------
__global__ __launch_bounds__(256) void k_prep(const float* __restrict__ feat,
                                              unsigned short* __restrict__ fb)
{
    __shared__ float t[CIN][CIN + 1];
    int blk = blockIdx.x;
    int b   = blk >> 8;
    int n0  = (blk & 255) << 6;
    int sub = threadIdx.x >> 6, lane = threadIdx.x & 63;
    const float* fp = feat + (size_t)b * CIN * NPTS;
    #pragma unroll
    for (int r = 0; r < CIN; r += 4) {
        int c = r + sub;
        t[c][lane] = fp[(size_t)c * NPTS + n0 + lane];     // coalesced along n
    }
    __syncthreads();
    unsigned short* ob = fb + (size_t)(b * NPTS + n0) * CIN;
    #pragma unroll
    for (int r = 0; r < CIN; r += 4) {
        int x = r + sub;
        ob[(size_t)x * CIN + lane] = f2bf(t[lane][x]);     // row n0+x, ch=lane
    }
}

// ---------------- K1: MFMA gather+attention+POOL, linear once per group ----------------
// Per wave: 16 points x 16 neighbors.
// Per k:  phase1 score^T[d,pt] = Wm x spir^T (8 MFMA); softmax over d (16 exp
//         + 2 shuffles); pooled[pt][d] += attn*spir accumulated IN REGISTERS.
// Per group (once): pooled -> bf16 -> plds transpose -> 16 MFMA with Wc.
//         This removes the 16x-redundant Wc MFMAs (256 -> 16 per group) and
//         the per-k bf16 pack + plds LDS round-trip from the critical path.
// Gather: 4-deep buffer ring, issue k+3 at iter k, steady-state vmcnt(6)
//         (counted, never drained mid-loop). LDS slices wave-private: NO
//         __syncthreads in main loop.
__global__ __launch_bounds__(256, 2) void k_main(
    const unsigned short* __restrict__ fb,   // [BNP][64] bf16
    const int* __restrict__ nidx,            // [BNP][16]
    const float* __restrict__ Wm,            // [64][64]
    const float* __restrict__ Wc,            // [128][64]
    float* __restrict__ out)                 // [4][128][16384], pre-BN
{
    // layout within a spir buffer (bytes): pt*64 + (ch&31)*2 + (ch>>5)*1024
    // == exactly global_load_lds's "base + lane*16" for lane=(pt<<2)|q
    __shared__ __align__(16) unsigned short spir[4][4][1024]; // 2KB/buf, 4-ring
    __shared__ __align__(16) unsigned short plds[4][16 * 72]; // pad 72: bank-safe
    __shared__ __align__(16) int            idxl[4][16 * 20]; // stride 20: 2-way max

    const int tid  = threadIdx.x;
    const int wv   = tid >> 6;
    const int lane = tid & 63;
    const int ptc  = lane & 15;     // MFMA n / m index
    const int qg   = lane >> 4;     // quad group
    const int pt4  = lane >> 2;     // gather row
    const int q4   = lane & 3;      // gather quarter

    // ---- weight A-fragments in registers: A[m=lane&15][k=qg*8+j (+32*ks)] ----
    short8 wmF[4][2];
    #pragma unroll
    for (int mt = 0; mt < 4; ++mt)
        #pragma unroll
        for (int ks = 0; ks < 2; ++ks) {
            const float* p = Wm + (size_t)(mt * 16 + ptc) * CIN + qg * 8 + ks * 32;
            short8 v;
            #pragma unroll
            for (int j = 0; j < 8; ++j) v[j] = (short)f2bf(p[j]);
            wmF[mt][ks] = v;
        }
    short8 wcF[8][2];
    #pragma unroll
    for (int mt = 0; mt < 8; ++mt)
        #pragma unroll
        for (int ks = 0; ks < 2; ++ks) {
            const float* p = Wc + (size_t)(mt * 16 + ptc) * CIN + qg * 8 + ks * 32;
            short8 v;
            #pragma unroll
            for (int j = 0; j < 8; ++j) v[j] = (short)f2bf(p[j]);
            wcF[mt][ks] = v;
        }

    for (int g = blockIdx.x * 4 + wv; g < BNP / KNB; g += 2048) {
        // stage this group's 256 neighbor indices
        i32x4 iv = *(const i32x4*)(nidx + (size_t)g * 256 + lane * 4);
        *(i32x4*)&idxl[wv][pt4 * 20 + q4 * 4] = iv;

        // async gather of neighbor k's 16 rows (2KB) into ring buf bf
        auto issue_gather = [&](int k, int bf) {
            int id = idxl[wv][pt4 * 20 + k];               // 4-lane broadcast read
            const unsigned short* gp = fb + (size_t)id * CIN + q4 * 8;
            __builtin_amdgcn_global_load_lds(
                (const __attribute__((address_space(1))) unsigned int*)(const void*)gp,
                (__attribute__((address_space(3))) unsigned int*)(void*)&spir[wv][bf][0],
                16, 0, 0);
            __builtin_amdgcn_global_load_lds(
                (const __attribute__((address_space(1))) unsigned int*)(const void*)(gp + 32),
                (__attribute__((address_space(3))) unsigned int*)(void*)&spir[wv][bf][512],
                16, 0, 0);
        };

        issue_gather(0, 0);
        issue_gather(1, 1);
        issue_gather(2, 2);

        f32x4 pool[4];
        #pragma unroll
        for (int i = 0; i < 4; ++i) pool[i] = (f32x4){0.f, 0.f, 0.f, 0.f};

        #pragma unroll
        for (int k = 0; k < KNB; ++k) {
            const int bf = k & 3;
            // refill ring: buf (k+3)&3 == (k-1)&3, fully consumed at iter k-1
            if (k + 3 < KNB) issue_gather(k + 3, (k + 3) & 3);
            // wait for buf k's 2 loads; leave up to 3 bufs (6 ops) in flight
            if      (k <= KNB - 4) WAITVM(6);
            else if (k == KNB - 3) WAITVM(4);
            else if (k == KNB - 2) WAITVM(2);
            else                   WAITVM(0);
            __asm__ volatile("" ::: "memory");

            // ---- phase 1: score^T[d, pt] = Wm x spir^T ----
            short8 b1_0 = *(const short8*)&spir[wv][bf][      ptc * 32 + qg * 8];
            short8 b1_1 = *(const short8*)&spir[wv][bf][512 + ptc * 32 + qg * 8];
            f32x4 zero4 = (f32x4){0.f, 0.f, 0.f, 0.f};
            f32x4 a1[4];
            #pragma unroll
            for (int mt = 0; mt < 4; ++mt) {
                f32x4 t0 = __builtin_amdgcn_mfma_f32_16x16x32_bf16(wmF[mt][0], b1_0, zero4, 0, 0, 0);
                a1[mt]   = __builtin_amdgcn_mfma_f32_16x16x32_bf16(wmF[mt][1], b1_1, t0,    0, 0, 0);
            }

            // ---- softmax over d (in-lane 16 + xor16/xor32) ----
            float e[16], s = 0.f;
            #pragma unroll
            for (int mt = 0; mt < 4; ++mt)
                #pragma unroll
                for (int r = 0; r < 4; ++r) {
                    float x = __expf(a1[mt][r]);
                    e[mt * 4 + r] = x;
                    s += x;
                }
            s += __shfl_xor(s, 16);
            s += __shfl_xor(s, 32);
            float inv = __builtin_amdgcn_rcpf(s);

            // ---- pooled[pt][d] += attn (.) spir  (pure register accumulate) ----
            #pragma unroll
            for (int mt = 0; mt < 4; ++mt) {
                // spir channels d0..d0+3, d0 = 16*mt + 4*qg (row ptc)
                u32x2 sv = *(const u32x2*)&spir[wv][bf]
                    [(mt >> 1) * 512 + ptc * 32 + (mt & 1) * 16 + qg * 4];
                unsigned lo = sv[0], hi = sv[1];
                pool[mt][0] = fmaf(bf2f((unsigned short)lo),         e[mt * 4 + 0] * inv, pool[mt][0]);
                pool[mt][1] = fmaf(bf2f((unsigned short)(lo >> 16)), e[mt * 4 + 1] * inv, pool[mt][1]);
                pool[mt][2] = fmaf(bf2f((unsigned short)hi),         e[mt * 4 + 2] * inv, pool[mt][2]);
                pool[mt][3] = fmaf(bf2f((unsigned short)(hi >> 16)), e[mt * 4 + 3] * inv, pool[mt][3]);
            }
        }

        // ---- per-group phase 2: pooled -> bf16 -> plds transpose -> B-frags ----
        #pragma unroll
        for (int mt = 0; mt < 4; ++mt) {
            unsigned w0 = ((__float_as_uint(pool[mt][0]) + 0x8000u) >> 16) |
                          ((__float_as_uint(pool[mt][1]) + 0x8000u) & 0xFFFF0000u);
            unsigned w1 = ((__float_as_uint(pool[mt][2]) + 0x8000u) >> 16) |
                          ((__float_as_uint(pool[mt][3]) + 0x8000u) & 0xFFFF0000u);
            *(u32x2*)&plds[wv][ptc * 72 + mt * 16 + qg * 4] = (u32x2){w0, w1};
        }
        short8 b2_0 = *(const short8*)&plds[wv][ptc * 72 +      qg * 8];
        short8 b2_1 = *(const short8*)&plds[wv][ptc * 72 + 32 + qg * 8];

        // D[o, pt] = Wc x pooled^T  (16 MFMAs per group, was 256)
        f32x4 acc2[8];
        #pragma unroll
        for (int mt = 0; mt < 8; ++mt) {
            f32x4 t0 = __builtin_amdgcn_mfma_f32_16x16x32_bf16(wcF[mt][0], b2_0,
                                                               (f32x4){0.f,0.f,0.f,0.f}, 0, 0, 0);
            acc2[mt] = __builtin_amdgcn_mfma_f32_16x16x32_bf16(wcF[mt][1], b2_1, t0, 0, 0, 0);
        }

        // ---- epilogue: C-layout store, out[b][o][n]  (b_conv absorbed by BN) ----
        int p0 = g * KNB;
        int b  = p0 >> 14;
        int nn = (p0 & (NPTS - 1)) + ptc;
        float* ob = out + (((size_t)b * COUT) << 14) + nn;
        #pragma unroll
        for (int mt = 0; mt < 8; ++mt)
            #pragma unroll
            for (int r = 0; r < 4; ++r)
                ob[((size_t)(mt * 16 + qg * 4 + r)) << 14] = acc2[mt][r];
    }
}

// ---------------- K2: deterministic BN partials, one block per (o, b) ----------------
__global__ __launch_bounds__(256) void k_part(const float* __restrict__ out,
                                              float* __restrict__ part)
{
    int o = blockIdx.x >> 2, b = blockIdx.x & 3;
    const float4* p = (const float4*)(out + (((size_t)(b * COUT + o)) << 14));
    float s = 0.f, q = 0.f;
    for (int i = threadIdx.x; i < NPTS / 4; i += 256) {
        float4 v = p[i];
        s += (v.x + v.y) + (v.z + v.w);
        q += (v.x * v.x + v.y * v.y) + (v.z * v.z + v.w * v.w);
    }
    #pragma unroll
    for (int off = 32; off >= 1; off >>= 1) {
        s += __shfl_xor(s, off);
        q += __shfl_xor(q, off);
    }
    __shared__ float ls[4], lq[4];
    if ((threadIdx.x & 63) == 0) { ls[threadIdx.x >> 6] = s; lq[threadIdx.x >> 6] = q; }
    __syncthreads();
    if (threadIdx.x == 0) {
        part[blockIdx.x * 2]     = (ls[0] + ls[1]) + (ls[2] + ls[3]);
        part[blockIdx.x * 2 + 1] = (lq[0] + lq[1]) + (lq[2] + lq[3]);
    }
}

// ---------------- K3: finalize stats per block + apply BN in place ----------------
__global__ __launch_bounds__(256) void k_apply(float* __restrict__ out,
                                               const float* __restrict__ part,
                                               const float* __restrict__ gamma,
                                               const float* __restrict__ beta)
{
    __shared__ float sc[COUT], sh[COUT];
    int t = threadIdx.x;
    if (t < COUT) {
        float s = 0.f, q = 0.f;
        #pragma unroll
        for (int j = 0; j < 4; ++j) {
            s += part[(t * 4 + j) * 2];
            q += part[(t * 4 + j) * 2 + 1];
        }
        float mean = s * (1.0f / BNP);
        float var  = q * (1.0f / BNP) - mean * mean;
        float a = gamma[t] * rsqrtf(var + BN_EPS);
        sc[t] = a; sh[t] = beta[t] - mean * a;
    }
    __syncthreads();
    const int total4 = BATCH * COUT * NPTS / 4;
    for (long i = (long)blockIdx.x * 256 + t; i < total4; i += (long)gridDim.x * 256) {
        int ch = ((int)(i >> 12)) & 127;
        float4 v = ((float4*)out)[i];
        float a = sc[ch], b2 = sh[ch];
        v.x = fmaf(v.x, a, b2); v.y = fmaf(v.y, a, b2);
        v.z = fmaf(v.z, a, b2); v.w = fmaf(v.w, a, b2);
        ((float4*)out)[i] = v;
    }
}

extern "C" void kernel_launch(void* const* d_in, const int* in_sizes, int n_in,
                              void* d_out, int out_size, void* d_ws, size_t ws_size,
                              hipStream_t stream)
{
    const float* feat  = (const float*)d_in[0];
    const int*   nidx  = (const int*)  d_in[1];
    // d_in[2] = permatrix (unused); d_in[5] = b_conv (exactly absorbed by BN)
    const float* Wm    = (const float*)d_in[3];
    const float* Wc    = (const float*)d_in[4];
    const float* gamma = (const float*)d_in[6];
    const float* beta  = (const float*)d_in[7];
    float* out = (float*)d_out;

    unsigned short* fb = (unsigned short*)d_ws;                        // 8.4 MB
    float* part = (float*)((char*)d_ws + (size_t)BNP * CIN * 2);       // 1024 floats

    k_prep <<<1024, 256, 0, stream>>>(feat, fb);
    k_main <<<512,  256, 0, stream>>>(fb, nidx, Wm, Wc, out);
    k_part <<<512,  256, 0, stream>>>(out, part);
    k_apply<<<2048, 256, 0, stream>>>(out, part, gamma, beta);
}